// Round 3
// baseline (86.544 us; speedup 1.0000x reference)
//
#include <hip/hip_runtime.h>
#include <cstdint>

// 5x5 local attention, B=2 H=128 W=128 C=64 BIN=64, fp32.
//
// R7: split cold ingestion from compute. The bench window is
//   [268MB poison fill | out-poison | OUR WORK], and the fill leaves L3
// (256MB) fully dirty. R5-probe established kernel cold=40us vs
// warm=13.7us; R4 vs R6 showed the 26us cold penalty is invariant to
// kernel structure/occupancy -> it is the dirty-L3 eviction storm paid
// by our barrier-synced miss pattern. The harness's own fills sustain
// 6.2 TB/s in the SAME dirty regime -> a pure barrier-free stream
// handles allocate+evict near peak. So R7 launches a streaming prefetch
// kernel (1 float4 per tensor per thread, 3x8.39MB, zero barriers, max
// MLP) to pull main/ref/refv into L3, then the unchanged R6 attention
// kernel runs L3-warm.
//
// Attention kernel body identical to R6 (verified, absmax 0.0078):
//  - ref + value tiles staged to LDS via global_load_lds width=16.
//  - interior blocks: pure affine, zero staging VALU.
//  - edge blocks: clamped value staging (masked), exact zero-pad ref.
//  - 25 ds_read_b128 scores, DPP 16-lane reduce, softmax over 25,
//    value FMAs from LDS. Single barrier.

#define BB 2
#define HH 128
#define WW 128
#define CC 64
#define KK 5
#define PAD 2
#define TC 20            // tile cols = 16 + 2*PAD
#define NV (KK * TC)     // 100 column-vectors per tile

template <int CTRL>
__device__ __forceinline__ float dpp_add(float v) {
    int r = __builtin_amdgcn_update_dpp(0, __float_as_int(v), CTRL, 0xF, 0xF, true);
    return v + __int_as_float(r);
}

// Sum across the 16 lanes of a DPP row (== one pixel group).
__device__ __forceinline__ float group16_sum(float v) {
    v = dpp_add<0xB1>(v);    // quad_perm xor 1
    v = dpp_add<0x4E>(v);    // quad_perm xor 2
    v = dpp_add<0x124>(v);   // row_ror:4
    v = dpp_add<0x128>(v);   // row_ror:8
    return v;
}

// Direct global->LDS, 16B per lane. LDS dest is wave-uniform base +
// lane*16 (the staging walk below produces exactly that layout).
__device__ __forceinline__ void lds_load16(const float* g, float* l) {
    __builtin_amdgcn_global_load_lds(
        (const __attribute__((address_space(1))) void*)(uintptr_t)g,
        (__attribute__((address_space(3))) void*)(uint32_t)(uintptr_t)l,
        16, 0, 0);
}

// ---- R7: cold-ingestion kernel. One float4 per tensor per thread ----
// 2048 blocks x 256 threads x 16B = 8.39MB = exactly one full tensor
// per stream. Pure reads, no barriers, results kept live via asm sink
// (rule #17) so the loads are not DCE'd.
__global__ __launch_bounds__(256) void prefetch_kernel(
    const float4* __restrict__ a,
    const float4* __restrict__ b,
    const float4* __restrict__ c)
{
    const size_t i = (size_t)blockIdx.x * 256 + threadIdx.x;
    const float4 x = a[i];
    const float4 y = b[i];
    const float4 z = c[i];
    asm volatile("" :: "v"(x.x), "v"(x.w), "v"(y.x), "v"(y.w),
                       "v"(z.x), "v"(z.w));
}

__global__ __launch_bounds__(256, 3) void local_attn_kernel(
    const float* __restrict__ mainp,
    const float* __restrict__ refp,
    const float* __restrict__ refvp,
    float* __restrict__ outp)
{
    __shared__ float reft[NV * CC];   // 25.6 KB zero-padded ref tile
    __shared__ float valt[NV * CC];   // 25.6 KB value tile (clamped at edges)

    const int tid    = threadIdx.x;
    const int lane16 = tid & 15;      // channel-quad index
    const int pix    = tid >> 4;      // local pixel 0..15
    const int seg    = blockIdx.x;    // 0..2047
    const int wseg   = seg & 7;
    const int h      = (seg >> 3) & (HH - 1);   // uniform per block
    const int b      = seg >> 10;
    const int w0     = wseg * 16;
    const int w      = w0 + pix;
    const int cb     = lane16 * 4;

    const size_t pbase = (((size_t)(b * HH + h)) * WW + w) * CC + cb;
    const float4 m4 = *reinterpret_cast<const float4*>(mainp + pbase);

    const bool interior = (wseg >= 1) & (wseg <= 6) & (h >= PAD) & (h < HH - PAD);
    const int v0base = (tid >> 6) * 4;   // wave-uniform LDS group base

    // ---- stage tiles: vector v=(r,c) -> tile[v*CC], one miss round ----
    {
        int r = 0, c = pix;            // v = pix, then v += 16 with wrap
        if (interior) {
            const size_t obase =
                (((size_t)(b * HH + h - PAD)) * WW + (w0 - PAD)) * CC + cb;
            #pragma unroll
            for (int i = 0; i < 7; ++i) {
                const int v0 = v0base + 16 * i;      // wave-uniform
                if (v0 < NV) {
                    const size_t off = obase + ((size_t)(r * WW + c)) * CC;
                    lds_load16(refp  + off, reft + (size_t)v0 * CC);
                    lds_load16(refvp + off, valt + (size_t)v0 * CC);
                }
                c += 16; const bool wr = (c >= TC); c = wr ? c - TC : c; r += wr;
            }
        } else {
            #pragma unroll
            for (int i = 0; i < 7; ++i) {
                const int v0 = v0base + 16 * i;      // wave-uniform
                if (v0 < NV) {
                    const int v   = pix + 16 * i;    // per-thread vector
                    const int hg  = h + r - PAD;
                    const int wg  = w0 + c - PAD;
                    const int hgc = min(max(hg, 0), HH - 1);
                    const int wgc = min(max(wg, 0), WW - 1);
                    const size_t coff =
                        (((size_t)(b * HH + hgc)) * WW + wgc) * CC + cb;
                    // value tile: clamped direct-to-LDS (masked later)
                    lds_load16(refvp + coff, valt + (size_t)v0 * CC);
                    // ref tile: register load + exact zero-pad select
                    const float4 d =
                        *reinterpret_cast<const float4*>(refp + coff);
                    const bool ok = ((unsigned)hg < (unsigned)HH) &
                                    ((unsigned)wg < (unsigned)WW);
                    float4 z;
                    z.x = ok ? d.x : 0.0f;
                    z.y = ok ? d.y : 0.0f;
                    z.z = ok ? d.z : 0.0f;
                    z.w = ok ? d.w : 0.0f;
                    *reinterpret_cast<float4*>(reft + (size_t)v * CC + cb) = z;
                }
                c += 16; const bool wr = (c >= TC); c = wr ? c - TC : c; r += wr;
            }
        }
    }
    __syncthreads();   // drains vmcnt (global_load_lds) + lgkmcnt

    // ---- scores: 25 ds_read_b128 with immediate offsets ----
    const float* tbase = reft + pix * CC + cb;
    float sc[KK * KK];
    #pragma unroll
    for (int r = 0; r < KK; ++r) {
        #pragma unroll
        for (int dj = 0; dj < KK; ++dj) {
            const float4 t =
                *reinterpret_cast<const float4*>(tbase + (r * TC + dj) * CC);
            sc[r * KK + dj] = m4.x * t.x + m4.y * t.y + m4.z * t.z + m4.w * t.w;
        }
    }

    // ---- reduce each score across the 16-lane group (VALU/DPP) ----
    #pragma unroll
    for (int p = 0; p < KK * KK; ++p) sc[p] = group16_sum(sc[p]);

    // ---- softmax over 25 (padded entries exactly 0, included) ----
    float mx = sc[0];
    #pragma unroll
    for (int p = 1; p < KK * KK; ++p) mx = fmaxf(mx, sc[p]);
    float ssum = 0.0f;
    #pragma unroll
    for (int p = 0; p < KK * KK; ++p) { sc[p] = __expf(sc[p] - mx); ssum += sc[p]; }
    const float inv = 1.0f / ssum;     // applied to acc at the end

    // ---- values from LDS tile (pixel pix, offset (di,dj) -> v=di*TC+pix+dj) ----
    const float* vtb = valt + pix * CC + cb;
    float4 acc = make_float4(0.f, 0.f, 0.f, 0.f);
    if (interior) {
        #pragma unroll
        for (int di = 0; di < KK; ++di) {
            #pragma unroll
            for (int dj = 0; dj < KK; ++dj) {
                const float4 v4 =
                    *reinterpret_cast<const float4*>(vtb + (di * TC + dj) * CC);
                const float a = sc[di * KK + dj];
                acc.x += a * v4.x;
                acc.y += a * v4.y;
                acc.z += a * v4.z;
                acc.w += a * v4.w;
            }
        }
    } else {
        float wokf[KK];
        #pragma unroll
        for (int dj = 0; dj < KK; ++dj) {
            const int ww_ = w + dj - PAD;
            wokf[dj] = ((unsigned)ww_ < (unsigned)WW) ? 1.0f : 0.0f;
        }
        #pragma unroll
        for (int di = 0; di < KK; ++di) {
            const int hh_   = h + di - PAD;
            const float hokf = ((unsigned)hh_ < (unsigned)HH) ? 1.0f : 0.0f;
            #pragma unroll
            for (int dj = 0; dj < KK; ++dj) {
                const float4 v4 =
                    *reinterpret_cast<const float4*>(vtb + (di * TC + dj) * CC);
                const float a = sc[di * KK + dj] * hokf * wokf[dj];
                acc.x += a * v4.x;
                acc.y += a * v4.y;
                acc.z += a * v4.z;
                acc.w += a * v4.w;
            }
        }
    }
    acc.x *= inv; acc.y *= inv; acc.z *= inv; acc.w *= inv;

    *reinterpret_cast<float4*>(outp + pbase) = acc;
}

extern "C" void kernel_launch(void* const* d_in, const int* in_sizes, int n_in,
                              void* d_out, int out_size, void* d_ws, size_t ws_size,
                              hipStream_t stream) {
    const float* mainp = (const float*)d_in[0];
    const float* refp  = (const float*)d_in[1];
    const float* refvp = (const float*)d_in[2];
    float* outp        = (float*)d_out;

    const int blocks = BB * HH * (WW / 16);  // 2048

    // R7: pure-stream cold ingestion of all three inputs (3 x 8.39MB),
    // paying the dirty-L3 eviction storm with fill-like efficiency.
    prefetch_kernel<<<blocks, 256, 0, stream>>>(
        (const float4*)mainp, (const float4*)refp, (const float4*)refvp);

    local_attn_kernel<<<blocks, 256, 0, stream>>>(mainp, refp, refvp, outp);
}